// Round 5
// baseline (752.716 us; speedup 1.0000x reference)
//
#include <hip/hip_runtime.h>

#define DEV __device__ __forceinline__

typedef _Float16 f16;
typedef _Float16 f16x8 __attribute__((ext_vector_type(8)));
typedef float f32x4 __attribute__((ext_vector_type(4)));

// ---------------------------------------------------------------- helpers

DEV void gload_lds16(const f16* g, f16* l) {
  // 16B-per-lane async global->LDS. LDS dest is wave-uniform base + lane*16.
  __builtin_amdgcn_global_load_lds(
      (const __attribute__((address_space(1))) void*)g,
      (__attribute__((address_space(3))) void*)l, 16, 0, 0);
}

// ---------------------------------------------------------------- prep

__global__ __launch_bounds__(256) void cast_f32_f16(const float* __restrict__ in,
                                                    f16* __restrict__ out, int n) {
  int i = (blockIdx.x * 256 + threadIdx.x) * 4;
  if (i < n) {
    float4 f = *(const float4*)(in + i);
    f16 o0 = (f16)f.x, o1 = (f16)f.y, o2 = (f16)f.z, o3 = (f16)f.w;
    f16* d = out + i;
    d[0] = o0; d[1] = o1; d[2] = o2; d[3] = o3;
  }
}

// transpose + cast 1024x1024 fp32 W -> f16 W^T   (z selects which weight)
__global__ __launch_bounds__(256) void transpose_cast(
    const float* s0, const float* s1, const float* s2, const float* s3,
    f16* d0, f16* d1, f16* d2, f16* d3) {
  const float* S[4] = {s0, s1, s2, s3};
  f16* D[4] = {d0, d1, d2, d3};
  const float* W = S[blockIdx.z];
  f16* WT = D[blockIdx.z];
  __shared__ float tile[32][33];
  int tx = threadIdx.x, ty = threadIdx.y;        // 32 x 8
  int r0 = blockIdx.y * 32, c0 = blockIdx.x * 32;
#pragma unroll
  for (int i = 0; i < 32; i += 8) tile[ty + i][tx] = W[(r0 + ty + i) * 1024 + c0 + tx];
  __syncthreads();
#pragma unroll
  for (int i = 0; i < 32; i += 8) WT[(c0 + ty + i) * 1024 + r0 + tx] = (f16)tile[tx][ty + i];
}

// ---------------------------------------------------------------- BT-GEMM core (m97)

DEV void gemm_bt_f16(const f16* __restrict__ A, const f16* __restrict__ B,
                     int lda, int ldb, int K, f16* As, f16* Bs, f32x4 (&acc)[4][4]) {
  const int t = threadIdx.x;
  const int l = t & 63, w = t >> 6;
  const int wm = w >> 1, wn = w & 1;
  const f16* ag = A + (t >> 2) * lda + (t & 3) * 8;
  const f16* bg = B + (t >> 2) * ldb + (t & 3) * 8;
  f16* asd = As + w * 512;
  f16* bsd = Bs + w * 512;
  const int arow = wm * 64 + (l & 15);
  const int brow = wn * 64 + (l & 15);
  const int ko = (l >> 4) * 8;
  for (int k0 = 0; k0 < K; k0 += 32) {
    __syncthreads();
    gload_lds16(ag + k0, asd);
    gload_lds16(ag + 64 * lda + k0, asd + 2048);
    gload_lds16(bg + k0, bsd);
    gload_lds16(bg + 64 * ldb + k0, bsd + 2048);
    __syncthreads();
    f16x8 af[4], bf[4];
#pragma unroll
    for (int i = 0; i < 4; i++) af[i] = *(const f16x8*)(As + (arow + i * 16) * 32 + ko);
#pragma unroll
    for (int j = 0; j < 4; j++) bf[j] = *(const f16x8*)(Bs + (brow + j * 16) * 32 + ko);
#pragma unroll
    for (int i = 0; i < 4; i++)
#pragma unroll
      for (int j = 0; j < 4; j++)
        acc[i][j] = __builtin_amdgcn_mfma_f32_16x16x32_f16(af[i], bf[j], acc[i][j], 0, 0, 0);
  }
}

// ---------------------------------------------------------------- K1: QKV projection

__global__ __launch_bounds__(256) void qkv_gemm(
    const f16* __restrict__ xb, const f16* __restrict__ WTq, const f16* __restrict__ WTk,
    const f16* __restrict__ WTv, const float* __restrict__ bq, const float* __restrict__ bk,
    const float* __restrict__ bv, f16* __restrict__ q, f16* __restrict__ kk,
    f16* __restrict__ vT) {
  __shared__ f16 As[128 * 32];
  __shared__ f16 Bs[128 * 32];
  __shared__ f16 tr[128 * 132];
  const int z = blockIdx.z;
  const f16* WT = (z == 0) ? WTq : ((z == 1) ? WTk : WTv);
  const float* bias = (z == 0) ? bq : ((z == 1) ? bk : bv);
  const int rowBase = blockIdx.y * 128, colBase = blockIdx.x * 128;
  f32x4 zero4 = {0.f, 0.f, 0.f, 0.f};
  f32x4 acc[4][4];
#pragma unroll
  for (int i = 0; i < 4; i++)
#pragma unroll
    for (int j = 0; j < 4; j++) acc[i][j] = zero4;
  gemm_bt_f16(xb + rowBase * 1024, WT + colBase * 1024, 1024, 1024, 1024, As, Bs, acc);
  const int t = threadIdx.x, l = t & 63, w = t >> 6, wm = w >> 1, wn = w & 1;
  if (z < 2) {
    f16* dst = (z == 0) ? q : kk;
#pragma unroll
    for (int i = 0; i < 4; i++)
#pragma unroll
      for (int j = 0; j < 4; j++)
#pragma unroll
        for (int r = 0; r < 4; r++) {
          int rt = wm * 64 + i * 16 + ((l >> 4) << 2) + r;
          int ct = wn * 64 + j * 16 + (l & 15);
          int rr = rowBase + rt, c = colBase + ct;
          float val = acc[i][j][r] + bias[c];
          int b = rr >> 10, n = rr & 1023, h = c >> 7, d = c & 127;
          dst[((b * 8 + h) * 1024 + n) * 128 + d] = (f16)val;
        }
  } else {
#pragma unroll
    for (int i = 0; i < 4; i++)
#pragma unroll
      for (int j = 0; j < 4; j++)
#pragma unroll
        for (int r = 0; r < 4; r++) {
          int rt = wm * 64 + i * 16 + ((l >> 4) << 2) + r;
          int ct = wn * 64 + j * 16 + (l & 15);
          tr[ct * 132 + rt] = (f16)(acc[i][j][r] + bias[colBase + ct]);
        }
    __syncthreads();
    int b = blockIdx.y >> 3, h = blockIdx.x;
    int nb = (blockIdx.y & 7) * 128;
    int head = b * 8 + h;
#pragma unroll
    for (int p = 0; p < 8; p++) {
      int lin = p * 2048 + t * 8;
      int c = lin >> 7, r = lin & 127;
      const f16* src = &tr[c * 132 + r];
      uint2 a0 = *(const uint2*)(src);
      uint2 a1 = *(const uint2*)(src + 4);
      f16* dst = vT + head * 131072 + c * 1024 + nb + r;
      *(uint2*)(dst) = a0;
      *(uint2*)(dst + 4) = a1;
    }
  }
}

// ---------------------------------------------------------------- K2: fused scores+entmax+PV, v3
// One block = (head, 16-row q strip). 512 threads = 8 waves. Barrier-free
// dataflow phases (B-fragments read directly from global; compiler pipelines
// MFMA <-> VMEM with vmcnt). Only LDS: 16x1032 f16 strip = 33 KB ->
// 4 blocks/CU = 32 waves/CU (full occupancy; __launch_bounds__(512,8)).
// Phase 1: S = q_strip @ K^T * SC -> Ps.                    (no barriers)
// Phase 2: entmax bisect, 2 rows/wave ILP-2; sm>=1 test (f_lo >= 0 always
//          since tau_lo = max-1 puts the max element's contribution at 1.0).
// Phase 3: ctx_strip = P @ V, A-frags from Ps, V from global. (no barriers)

#define PSLD 1032  // +8 pad

__global__ __launch_bounds__(512, 8) void fused_attn(
    const f16* __restrict__ q, const f16* __restrict__ kk,
    const f16* __restrict__ vT, float* __restrict__ attn, f16* __restrict__ ctx) {
  __shared__ f16 Ps[16 * PSLD];  // 33 KB
  const int t = threadIdx.x, l = t & 63, w = t >> 6;
  const int head = blockIdx.y, n0 = blockIdx.x * 16;
  const int l15 = l & 15, l16 = l >> 4;
  const int bb = head >> 3, hh = head & 7;
  const float SC = 0.04419417382415922f;  // (alpha-1)/sqrt(D) = 0.5/sqrt(128)

  const f16* qh = q + head * 131072;
  const f16* kh = kk + head * 131072;
  const f16* vh = vT + head * 131072;

  // q A-fragments (rows n0..n0+15), kept in registers
  f16x8 qf[4];
#pragma unroll
  for (int kb = 0; kb < 4; kb++)
    qf[kb] = *(const f16x8*)(qh + (n0 + l15) * 128 + kb * 32 + l16 * 8);

  // ---- phase 1: scores (wave w owns n-tiles w*8 .. w*8+7) ---------------
#pragma unroll 2
  for (int i = 0; i < 8; i++) {
    const int nt = w * 8 + i;
    f16x8 bf[4];
#pragma unroll
    for (int kb = 0; kb < 4; kb++)
      bf[kb] = *(const f16x8*)(kh + (nt * 16 + l15) * 128 + kb * 32 + l16 * 8);
    f32x4 acc = {0.f, 0.f, 0.f, 0.f};
#pragma unroll
    for (int kb = 0; kb < 4; kb++)
      acc = __builtin_amdgcn_mfma_f32_16x16x32_f16(qf[kb], bf[kb], acc, 0, 0, 0);
#pragma unroll
    for (int r = 0; r < 4; r++)
      Ps[(l16 * 4 + r) * PSLD + nt * 16 + l15] = (f16)(acc[r] * SC);
  }
  __syncthreads();

  // ---- phase 2: entmax (wave w owns rows w*2, w*2+1; ILP-2) -------------
  {
    f16* r0p = Ps + (size_t)(w * 2) * PSLD;
    f16* r1p = r0p + PSLD;
    f16x8 a0 = *(const f16x8*)(r0p + l * 8);
    f16x8 a1 = *(const f16x8*)(r0p + 512 + l * 8);
    f16x8 c0 = *(const f16x8*)(r1p + l * 8);
    f16x8 c1 = *(const f16x8*)(r1p + 512 + l * 8);
    float x0[16], x1[16];
#pragma unroll
    for (int e = 0; e < 8; e++) {
      x0[e] = (float)a0[e]; x0[8 + e] = (float)a1[e];
      x1[e] = (float)c0[e]; x1[8 + e] = (float)c1[e];
    }
    float m0 = x0[0], m1 = x1[0];
#pragma unroll
    for (int e = 1; e < 16; e++) { m0 = fmaxf(m0, x0[e]); m1 = fmaxf(m1, x1[e]); }
#pragma unroll
    for (int o = 32; o; o >>= 1) {
      m0 = fmaxf(m0, __shfl_xor(m0, o, 64));
      m1 = fmaxf(m1, __shfl_xor(m1, o, 64));
    }
    float lo0 = m0 - 1.0f, lo1 = m1 - 1.0f;
    float dm = 0.96875f;  // 1 - (1/1024)^(alpha-1)
    float tm0 = lo0, tm1 = lo1;
    for (int it = 0; it < 13; ++it) {
      dm *= 0.5f;
      tm0 = lo0 + dm; tm1 = lo1 + dm;
      float a0s = 0.f, a1s = 0.f;
#pragma unroll
      for (int e = 0; e < 16; e++) {
        float a = fmaxf(x0[e] - tm0, 0.f); a0s = fmaf(a, a, a0s);
        float b = fmaxf(x1[e] - tm1, 0.f); a1s = fmaf(b, b, a1s);
      }
#pragma unroll
      for (int o = 32; o; o >>= 1) { a0s += __shfl_xor(a0s, o, 64); a1s += __shfl_xor(a1s, o, 64); }
      if (a0s >= 1.0f) lo0 = tm0;
      if (a1s >= 1.0f) lo1 = tm1;
    }
    float q0 = 0.f, q1 = 0.f;
#pragma unroll
    for (int e = 0; e < 16; e++) {
      float a = fmaxf(x0[e] - tm0, 0.f); x0[e] = a * a; q0 += x0[e];
      float b = fmaxf(x1[e] - tm1, 0.f); x1[e] = b * b; q1 += x1[e];
    }
#pragma unroll
    for (int o = 32; o; o >>= 1) { q0 += __shfl_xor(q0, o, 64); q1 += __shfl_xor(q1, o, 64); }
    float i0 = 1.0f / q0, i1 = 1.0f / q1;
    float* a0p = attn + ((size_t)head * 1024 + n0 + w * 2) * 1024;
    float* a1p = a0p + 1024;
    float4 v0 = {x0[0] * i0, x0[1] * i0, x0[2] * i0, x0[3] * i0};
    float4 v1 = {x0[4] * i0, x0[5] * i0, x0[6] * i0, x0[7] * i0};
    float4 v2 = {x0[8] * i0, x0[9] * i0, x0[10] * i0, x0[11] * i0};
    float4 v3 = {x0[12] * i0, x0[13] * i0, x0[14] * i0, x0[15] * i0};
    float4 u0 = {x1[0] * i1, x1[1] * i1, x1[2] * i1, x1[3] * i1};
    float4 u1 = {x1[4] * i1, x1[5] * i1, x1[6] * i1, x1[7] * i1};
    float4 u2 = {x1[8] * i1, x1[9] * i1, x1[10] * i1, x1[11] * i1};
    float4 u3 = {x1[12] * i1, x1[13] * i1, x1[14] * i1, x1[15] * i1};
    *(float4*)(a0p + l * 8) = v0;
    *(float4*)(a0p + l * 8 + 4) = v1;
    *(float4*)(a0p + 512 + l * 8) = v2;
    *(float4*)(a0p + 512 + l * 8 + 4) = v3;
    *(float4*)(a1p + l * 8) = u0;
    *(float4*)(a1p + l * 8 + 4) = u1;
    *(float4*)(a1p + 512 + l * 8) = u2;
    *(float4*)(a1p + 512 + l * 8 + 4) = u3;
    f16x8 o0 = {(f16)v0.x, (f16)v0.y, (f16)v0.z, (f16)v0.w,
                (f16)v1.x, (f16)v1.y, (f16)v1.z, (f16)v1.w};
    f16x8 o1 = {(f16)v2.x, (f16)v2.y, (f16)v2.z, (f16)v2.w,
                (f16)v3.x, (f16)v3.y, (f16)v3.z, (f16)v3.w};
    f16x8 o2 = {(f16)u0.x, (f16)u0.y, (f16)u0.z, (f16)u0.w,
                (f16)u1.x, (f16)u1.y, (f16)u1.z, (f16)u1.w};
    f16x8 o3 = {(f16)u2.x, (f16)u2.y, (f16)u2.z, (f16)u2.w,
                (f16)u3.x, (f16)u3.y, (f16)u3.z, (f16)u3.w};
    *(f16x8*)(r0p + l * 8) = o0;
    *(f16x8*)(r0p + 512 + l * 8) = o1;
    *(f16x8*)(r1p + l * 8) = o2;
    *(f16x8*)(r1p + 512 + l * 8) = o3;
  }
  __syncthreads();

  // ---- phase 3: ctx = P @ V (wave w owns d-tile w; K=1024 dataflow) -----
  f32x4 cacc = {0.f, 0.f, 0.f, 0.f};
#pragma unroll 4
  for (int kb = 0; kb < 32; kb++) {
    f16x8 bfv = *(const f16x8*)(vh + (w * 16 + l15) * 1024 + kb * 32 + l16 * 8);
    f16x8 af = *(const f16x8*)(Ps + l15 * PSLD + kb * 32 + l16 * 8);
    cacc = __builtin_amdgcn_mfma_f32_16x16x32_f16(af, bfv, cacc, 0, 0, 0);
  }
#pragma unroll
  for (int r = 0; r < 4; r++) {
    int m = l16 * 4 + r;
    int d = w * 16 + l15;
    ctx[(size_t)(bb * 1024 + n0 + m) * 1024 + hh * 128 + d] = (f16)cacc[r];
  }
}

// ---------------------------------------------------------------- K3: out = ctx @ Wo + bo

__global__ __launch_bounds__(256) void out_gemm(const f16* __restrict__ ctx,
                                                const f16* __restrict__ WTo,
                                                const float* __restrict__ bo,
                                                float* __restrict__ out) {
  __shared__ f16 As[128 * 32];
  __shared__ f16 Bs[128 * 32];
  const int rowBase = blockIdx.y * 128, colBase = blockIdx.x * 128;
  f32x4 zero4 = {0.f, 0.f, 0.f, 0.f};
  f32x4 acc[4][4];
#pragma unroll
  for (int i = 0; i < 4; i++)
#pragma unroll
    for (int j = 0; j < 4; j++) acc[i][j] = zero4;
  gemm_bt_f16(ctx + rowBase * 1024, WTo + colBase * 1024, 1024, 1024, 1024, As, Bs, acc);
  const int l = threadIdx.x & 63, w = threadIdx.x >> 6, wm = w >> 1, wn = w & 1;
#pragma unroll
  for (int i = 0; i < 4; i++)
#pragma unroll
    for (int j = 0; j < 4; j++)
#pragma unroll
      for (int r = 0; r < 4; r++) {
        int rt = wm * 64 + i * 16 + ((l >> 4) << 2) + r;
        int ct = wn * 64 + j * 16 + (l & 15);
        out[(size_t)(rowBase + rt) * 1024 + colBase + ct] = acc[i][j][r] + bo[colBase + ct];
      }
}

// ---------------------------------------------------------------- launch

extern "C" void kernel_launch(void* const* d_in, const int* in_sizes, int n_in,
                              void* d_out, int out_size, void* d_ws, size_t ws_size,
                              hipStream_t stream) {
  const float* x  = (const float*)d_in[0];
  const float* Wq = (const float*)d_in[1];
  const float* bq = (const float*)d_in[2];
  const float* Wk = (const float*)d_in[3];
  const float* bk = (const float*)d_in[4];
  const float* Wv = (const float*)d_in[5];
  const float* bv = (const float*)d_in[6];
  const float* Wo = (const float*)d_in[7];
  const float* bo = (const float*)d_in[8];
  float* out = (float*)d_out;
  float* attn = out + 8388608;  // [64 heads][1024][1024] fp32 output

  char* ws = (char*)d_ws;
  f16* xb  = (f16*)(ws);                     // 16MB  (reused as ctx after qkv)
  f16* ctx = (f16*)(ws);                     // alias of xb
  f16* WTq = (f16*)(ws + (16u << 20));       // 2MB each
  f16* WTk = (f16*)(ws + (18u << 20));
  f16* WTv = (f16*)(ws + (20u << 20));
  f16* WTo = (f16*)(ws + (22u << 20));
  f16* q   = (f16*)(ws + (24u << 20));       // 16MB [64][1024][128]
  f16* kk  = (f16*)(ws + (40u << 20));       // 16MB
  f16* vT  = (f16*)(ws + (56u << 20));       // 16MB [64][128][1024]
  // total ws use: 72MB

  cast_f32_f16<<<dim3(8192), dim3(256), 0, stream>>>(x, xb, 8388608);
  transpose_cast<<<dim3(32, 32, 4), dim3(32, 8), 0, stream>>>(
      Wq, Wk, Wv, Wo, WTq, WTk, WTv, WTo);
  qkv_gemm<<<dim3(8, 64, 3), dim3(256), 0, stream>>>(
      xb, WTq, WTk, WTv, bq, bk, bv, q, kk, vT);
  fused_attn<<<dim3(64, 64), dim3(512), 0, stream>>>(q, kk, vT, attn, ctx);
  out_gemm<<<dim3(8, 64), dim3(256), 0, stream>>>(ctx, WTo, bo, out);
}

// Round 6
// 605.535 us; speedup vs baseline: 1.2431x; 1.2431x over previous
//
#include <hip/hip_runtime.h>

#define DEV __device__ __forceinline__

typedef _Float16 f16;
typedef _Float16 f16x8 __attribute__((ext_vector_type(8)));
typedef float f32x4 __attribute__((ext_vector_type(4)));

// ---------------------------------------------------------------- helpers

DEV void gload_lds16(const f16* g, f16* l) {
  // 16B-per-lane async global->LDS. LDS dest is wave-uniform base + lane*16.
  __builtin_amdgcn_global_load_lds(
      (const __attribute__((address_space(1))) void*)g,
      (__attribute__((address_space(3))) void*)l, 16, 0, 0);
}

// ---------------------------------------------------------------- prep

__global__ __launch_bounds__(256) void cast_f32_f16(const float* __restrict__ in,
                                                    f16* __restrict__ out, int n) {
  int i = (blockIdx.x * 256 + threadIdx.x) * 4;
  if (i < n) {
    float4 f = *(const float4*)(in + i);
    f16 o0 = (f16)f.x, o1 = (f16)f.y, o2 = (f16)f.z, o3 = (f16)f.w;
    f16* d = out + i;
    d[0] = o0; d[1] = o1; d[2] = o2; d[3] = o3;
  }
}

// transpose + cast 1024x1024 fp32 W -> f16 W^T   (z selects which weight)
__global__ __launch_bounds__(256) void transpose_cast(
    const float* s0, const float* s1, const float* s2, const float* s3,
    f16* d0, f16* d1, f16* d2, f16* d3) {
  const float* S[4] = {s0, s1, s2, s3};
  f16* D[4] = {d0, d1, d2, d3};
  const float* W = S[blockIdx.z];
  f16* WT = D[blockIdx.z];
  __shared__ float tile[32][33];
  int tx = threadIdx.x, ty = threadIdx.y;        // 32 x 8
  int r0 = blockIdx.y * 32, c0 = blockIdx.x * 32;
#pragma unroll
  for (int i = 0; i < 32; i += 8) tile[ty + i][tx] = W[(r0 + ty + i) * 1024 + c0 + tx];
  __syncthreads();
#pragma unroll
  for (int i = 0; i < 32; i += 8) WT[(c0 + ty + i) * 1024 + r0 + tx] = (f16)tile[tx][ty + i];
}

// ---------------------------------------------------------------- BT-GEMM core (m97)

DEV void gemm_bt_f16(const f16* __restrict__ A, const f16* __restrict__ B,
                     int lda, int ldb, int K, f16* As, f16* Bs, f32x4 (&acc)[4][4]) {
  const int t = threadIdx.x;
  const int l = t & 63, w = t >> 6;
  const int wm = w >> 1, wn = w & 1;
  const f16* ag = A + (t >> 2) * lda + (t & 3) * 8;
  const f16* bg = B + (t >> 2) * ldb + (t & 3) * 8;
  f16* asd = As + w * 512;
  f16* bsd = Bs + w * 512;
  const int arow = wm * 64 + (l & 15);
  const int brow = wn * 64 + (l & 15);
  const int ko = (l >> 4) * 8;
  for (int k0 = 0; k0 < K; k0 += 32) {
    __syncthreads();
    gload_lds16(ag + k0, asd);
    gload_lds16(ag + 64 * lda + k0, asd + 2048);
    gload_lds16(bg + k0, bsd);
    gload_lds16(bg + 64 * ldb + k0, bsd + 2048);
    __syncthreads();
    f16x8 af[4], bf[4];
#pragma unroll
    for (int i = 0; i < 4; i++) af[i] = *(const f16x8*)(As + (arow + i * 16) * 32 + ko);
#pragma unroll
    for (int j = 0; j < 4; j++) bf[j] = *(const f16x8*)(Bs + (brow + j * 16) * 32 + ko);
#pragma unroll
    for (int i = 0; i < 4; i++)
#pragma unroll
      for (int j = 0; j < 4; j++)
        acc[i][j] = __builtin_amdgcn_mfma_f32_16x16x32_f16(af[i], bf[j], acc[i][j], 0, 0, 0);
  }
}

// ---------------------------------------------------------------- K1: QKV projection

__global__ __launch_bounds__(256) void qkv_gemm(
    const f16* __restrict__ xb, const f16* __restrict__ WTq, const f16* __restrict__ WTk,
    const f16* __restrict__ WTv, const float* __restrict__ bq, const float* __restrict__ bk,
    const float* __restrict__ bv, f16* __restrict__ q, f16* __restrict__ kk,
    f16* __restrict__ vT) {
  __shared__ f16 As[128 * 32];
  __shared__ f16 Bs[128 * 32];
  __shared__ f16 tr[128 * 132];
  const int z = blockIdx.z;
  const f16* WT = (z == 0) ? WTq : ((z == 1) ? WTk : WTv);
  const float* bias = (z == 0) ? bq : ((z == 1) ? bk : bv);
  const int rowBase = blockIdx.y * 128, colBase = blockIdx.x * 128;
  f32x4 zero4 = {0.f, 0.f, 0.f, 0.f};
  f32x4 acc[4][4];
#pragma unroll
  for (int i = 0; i < 4; i++)
#pragma unroll
    for (int j = 0; j < 4; j++) acc[i][j] = zero4;
  gemm_bt_f16(xb + rowBase * 1024, WT + colBase * 1024, 1024, 1024, 1024, As, Bs, acc);
  const int t = threadIdx.x, l = t & 63, w = t >> 6, wm = w >> 1, wn = w & 1;
  if (z < 2) {
    f16* dst = (z == 0) ? q : kk;
#pragma unroll
    for (int i = 0; i < 4; i++)
#pragma unroll
      for (int j = 0; j < 4; j++)
#pragma unroll
        for (int r = 0; r < 4; r++) {
          int rt = wm * 64 + i * 16 + ((l >> 4) << 2) + r;
          int ct = wn * 64 + j * 16 + (l & 15);
          int rr = rowBase + rt, c = colBase + ct;
          float val = acc[i][j][r] + bias[c];
          int b = rr >> 10, n = rr & 1023, h = c >> 7, d = c & 127;
          dst[((b * 8 + h) * 1024 + n) * 128 + d] = (f16)val;
        }
  } else {
#pragma unroll
    for (int i = 0; i < 4; i++)
#pragma unroll
      for (int j = 0; j < 4; j++)
#pragma unroll
        for (int r = 0; r < 4; r++) {
          int rt = wm * 64 + i * 16 + ((l >> 4) << 2) + r;
          int ct = wn * 64 + j * 16 + (l & 15);
          tr[ct * 132 + rt] = (f16)(acc[i][j][r] + bias[colBase + ct]);
        }
    __syncthreads();
    int b = blockIdx.y >> 3, h = blockIdx.x;
    int nb = (blockIdx.y & 7) * 128;
    int head = b * 8 + h;
#pragma unroll
    for (int p = 0; p < 8; p++) {
      int lin = p * 2048 + t * 8;
      int c = lin >> 7, r = lin & 127;
      const f16* src = &tr[c * 132 + r];
      uint2 a0 = *(const uint2*)(src);
      uint2 a1 = *(const uint2*)(src + 4);
      f16* dst = vT + head * 131072 + c * 1024 + nb + r;
      *(uint2*)(dst) = a0;
      *(uint2*)(dst + 4) = a1;
    }
  }
}

// ---------------------------------------------------------------- K2: fused scores+entmax+PV, v4
// R4 structure (M=32 strip, 66 KB LDS, barrier-free dataflow phases) plus:
//  * XCD-aware mapping: 1-D grid, xcd = b&7 (round-robin dispatch), all 32
//    strips of a head run on ONE XCD -> K/V stay resident in that XCD's 4MB
//    L2 (~2 heads x 0.5MB concurrent). Attacks the measured 2TB/s effective
//    ceiling (R5: FETCH doubled when locality broke).
//  * Deeper unroll: phase-1 x4 (16 b128 in flight), phase-3 x8.
// Phase 2 entmax: sm>=1 bisection test (f_lo>=0 always), 13 iters.

#define PSLD 1032  // +8 pad

__global__ __launch_bounds__(512, 4) void fused_attn(
    const f16* __restrict__ q, const f16* __restrict__ kk,
    const f16* __restrict__ vT, float* __restrict__ attn, f16* __restrict__ ctx) {
  __shared__ f16 Ps[32 * PSLD];  // 66 KB
  const int t = threadIdx.x, l = t & 63, w = t >> 6;
  const int blk = blockIdx.x;          // 0..2047
  const int xcd = blk & 7;
  const int slot = blk >> 3;           // 0..255
  const int head = xcd * 8 + (slot >> 5);
  const int n0 = (slot & 31) * 32;
  const int l15 = l & 15, l16 = l >> 4;
  const int bb = head >> 3, hh = head & 7;
  const float SC = 0.04419417382415922f;  // (alpha-1)/sqrt(D) = 0.5/sqrt(128)

  const f16* qh = q + head * 131072;
  const f16* kh = kk + head * 131072;
  const f16* vh = vT + head * 131072;

  // q A-fragments for both m-tiles (rows n0..n0+31), kept in registers
  f16x8 qf[2][4];
#pragma unroll
  for (int mt = 0; mt < 2; mt++)
#pragma unroll
    for (int kb = 0; kb < 4; kb++)
      qf[mt][kb] = *(const f16x8*)(qh + (n0 + mt * 16 + l15) * 128 + kb * 32 + l16 * 8);

  // ---- phase 1: scores (wave w owns n-tiles w*8 .. w*8+7) ---------------
#pragma unroll 4
  for (int i = 0; i < 8; i++) {
    const int nt = w * 8 + i;
    f16x8 bf[4];
#pragma unroll
    for (int kb = 0; kb < 4; kb++)
      bf[kb] = *(const f16x8*)(kh + (nt * 16 + l15) * 128 + kb * 32 + l16 * 8);
    f32x4 acc[2] = {{0.f, 0.f, 0.f, 0.f}, {0.f, 0.f, 0.f, 0.f}};
#pragma unroll
    for (int mt = 0; mt < 2; mt++)
#pragma unroll
      for (int kb = 0; kb < 4; kb++)
        acc[mt] = __builtin_amdgcn_mfma_f32_16x16x32_f16(qf[mt][kb], bf[kb], acc[mt], 0, 0, 0);
#pragma unroll
    for (int mt = 0; mt < 2; mt++)
#pragma unroll
      for (int r = 0; r < 4; r++)
        Ps[(mt * 16 + l16 * 4 + r) * PSLD + nt * 16 + l15] = (f16)(acc[mt][r] * SC);
  }
  __syncthreads();

  // ---- phase 2: entmax (wave w owns rows w*4..w*4+3; two ILP-2 passes) --
  for (int p = 0; p < 2; p++) {
    f16* r0p = Ps + (size_t)(w * 4 + p * 2) * PSLD;
    f16* r1p = r0p + PSLD;
    f16x8 a0 = *(const f16x8*)(r0p + l * 8);
    f16x8 a1 = *(const f16x8*)(r0p + 512 + l * 8);
    f16x8 c0 = *(const f16x8*)(r1p + l * 8);
    f16x8 c1 = *(const f16x8*)(r1p + 512 + l * 8);
    float x0[16], x1[16];
#pragma unroll
    for (int e = 0; e < 8; e++) {
      x0[e] = (float)a0[e]; x0[8 + e] = (float)a1[e];
      x1[e] = (float)c0[e]; x1[8 + e] = (float)c1[e];
    }
    float m0 = x0[0], m1 = x1[0];
#pragma unroll
    for (int e = 1; e < 16; e++) { m0 = fmaxf(m0, x0[e]); m1 = fmaxf(m1, x1[e]); }
#pragma unroll
    for (int o = 32; o; o >>= 1) {
      m0 = fmaxf(m0, __shfl_xor(m0, o, 64));
      m1 = fmaxf(m1, __shfl_xor(m1, o, 64));
    }
    float lo0 = m0 - 1.0f, lo1 = m1 - 1.0f;
    float dm = 0.96875f;  // 1 - (1/1024)^(alpha-1)
    float tm0 = lo0, tm1 = lo1;
    for (int it = 0; it < 13; ++it) {
      dm *= 0.5f;
      tm0 = lo0 + dm; tm1 = lo1 + dm;
      float a0s = 0.f, a1s = 0.f;
#pragma unroll
      for (int e = 0; e < 16; e++) {
        float a = fmaxf(x0[e] - tm0, 0.f); a0s = fmaf(a, a, a0s);
        float b = fmaxf(x1[e] - tm1, 0.f); a1s = fmaf(b, b, a1s);
      }
#pragma unroll
      for (int o = 32; o; o >>= 1) { a0s += __shfl_xor(a0s, o, 64); a1s += __shfl_xor(a1s, o, 64); }
      if (a0s >= 1.0f) lo0 = tm0;
      if (a1s >= 1.0f) lo1 = tm1;
    }
    float q0 = 0.f, q1 = 0.f;
#pragma unroll
    for (int e = 0; e < 16; e++) {
      float a = fmaxf(x0[e] - tm0, 0.f); x0[e] = a * a; q0 += x0[e];
      float b = fmaxf(x1[e] - tm1, 0.f); x1[e] = b * b; q1 += x1[e];
    }
#pragma unroll
    for (int o = 32; o; o >>= 1) { q0 += __shfl_xor(q0, o, 64); q1 += __shfl_xor(q1, o, 64); }
    float i0 = 1.0f / q0, i1 = 1.0f / q1;
    float* a0p = attn + ((size_t)head * 1024 + n0 + w * 4 + p * 2) * 1024;
    float* a1p = a0p + 1024;
    float4 v0 = {x0[0] * i0, x0[1] * i0, x0[2] * i0, x0[3] * i0};
    float4 v1 = {x0[4] * i0, x0[5] * i0, x0[6] * i0, x0[7] * i0};
    float4 v2 = {x0[8] * i0, x0[9] * i0, x0[10] * i0, x0[11] * i0};
    float4 v3 = {x0[12] * i0, x0[13] * i0, x0[14] * i0, x0[15] * i0};
    float4 u0 = {x1[0] * i1, x1[1] * i1, x1[2] * i1, x1[3] * i1};
    float4 u1 = {x1[4] * i1, x1[5] * i1, x1[6] * i1, x1[7] * i1};
    float4 u2 = {x1[8] * i1, x1[9] * i1, x1[10] * i1, x1[11] * i1};
    float4 u3 = {x1[12] * i1, x1[13] * i1, x1[14] * i1, x1[15] * i1};
    *(float4*)(a0p + l * 8) = v0;
    *(float4*)(a0p + l * 8 + 4) = v1;
    *(float4*)(a0p + 512 + l * 8) = v2;
    *(float4*)(a0p + 512 + l * 8 + 4) = v3;
    *(float4*)(a1p + l * 8) = u0;
    *(float4*)(a1p + l * 8 + 4) = u1;
    *(float4*)(a1p + 512 + l * 8) = u2;
    *(float4*)(a1p + 512 + l * 8 + 4) = u3;
    f16x8 o0 = {(f16)v0.x, (f16)v0.y, (f16)v0.z, (f16)v0.w,
                (f16)v1.x, (f16)v1.y, (f16)v1.z, (f16)v1.w};
    f16x8 o1 = {(f16)v2.x, (f16)v2.y, (f16)v2.z, (f16)v2.w,
                (f16)v3.x, (f16)v3.y, (f16)v3.z, (f16)v3.w};
    f16x8 o2 = {(f16)u0.x, (f16)u0.y, (f16)u0.z, (f16)u0.w,
                (f16)u1.x, (f16)u1.y, (f16)u1.z, (f16)u1.w};
    f16x8 o3 = {(f16)u2.x, (f16)u2.y, (f16)u2.z, (f16)u2.w,
                (f16)u3.x, (f16)u3.y, (f16)u3.z, (f16)u3.w};
    *(f16x8*)(r0p + l * 8) = o0;
    *(f16x8*)(r0p + 512 + l * 8) = o1;
    *(f16x8*)(r1p + l * 8) = o2;
    *(f16x8*)(r1p + 512 + l * 8) = o3;
  }
  __syncthreads();

  // ---- phase 3: ctx = P @ V (wave w owns d-tile w; K=1024 dataflow) -----
  f32x4 cacc[2] = {{0.f, 0.f, 0.f, 0.f}, {0.f, 0.f, 0.f, 0.f}};
#pragma unroll 8
  for (int kb = 0; kb < 32; kb++) {
    f16x8 bfv = *(const f16x8*)(vh + (w * 16 + l15) * 1024 + kb * 32 + l16 * 8);
    f16x8 af0 = *(const f16x8*)(Ps + l15 * PSLD + kb * 32 + l16 * 8);
    f16x8 af1 = *(const f16x8*)(Ps + (16 + l15) * PSLD + kb * 32 + l16 * 8);
    cacc[0] = __builtin_amdgcn_mfma_f32_16x16x32_f16(af0, bfv, cacc[0], 0, 0, 0);
    cacc[1] = __builtin_amdgcn_mfma_f32_16x16x32_f16(af1, bfv, cacc[1], 0, 0, 0);
  }
#pragma unroll
  for (int mt = 0; mt < 2; mt++)
#pragma unroll
    for (int r = 0; r < 4; r++) {
      int m = mt * 16 + l16 * 4 + r;
      int d = w * 16 + l15;
      ctx[(size_t)(bb * 1024 + n0 + m) * 1024 + hh * 128 + d] = (f16)cacc[mt][r];
    }
}

// ---------------------------------------------------------------- K3: out = ctx @ Wo + bo

__global__ __launch_bounds__(256) void out_gemm(const f16* __restrict__ ctx,
                                                const f16* __restrict__ WTo,
                                                const float* __restrict__ bo,
                                                float* __restrict__ out) {
  __shared__ f16 As[128 * 32];
  __shared__ f16 Bs[128 * 32];
  const int rowBase = blockIdx.y * 128, colBase = blockIdx.x * 128;
  f32x4 zero4 = {0.f, 0.f, 0.f, 0.f};
  f32x4 acc[4][4];
#pragma unroll
  for (int i = 0; i < 4; i++)
#pragma unroll
    for (int j = 0; j < 4; j++) acc[i][j] = zero4;
  gemm_bt_f16(ctx + rowBase * 1024, WTo + colBase * 1024, 1024, 1024, 1024, As, Bs, acc);
  const int l = threadIdx.x & 63, w = threadIdx.x >> 6, wm = w >> 1, wn = w & 1;
#pragma unroll
  for (int i = 0; i < 4; i++)
#pragma unroll
    for (int j = 0; j < 4; j++)
#pragma unroll
      for (int r = 0; r < 4; r++) {
        int rt = wm * 64 + i * 16 + ((l >> 4) << 2) + r;
        int ct = wn * 64 + j * 16 + (l & 15);
        out[(size_t)(rowBase + rt) * 1024 + colBase + ct] = acc[i][j][r] + bo[colBase + ct];
      }
}

// ---------------------------------------------------------------- launch

extern "C" void kernel_launch(void* const* d_in, const int* in_sizes, int n_in,
                              void* d_out, int out_size, void* d_ws, size_t ws_size,
                              hipStream_t stream) {
  const float* x  = (const float*)d_in[0];
  const float* Wq = (const float*)d_in[1];
  const float* bq = (const float*)d_in[2];
  const float* Wk = (const float*)d_in[3];
  const float* bk = (const float*)d_in[4];
  const float* Wv = (const float*)d_in[5];
  const float* bv = (const float*)d_in[6];
  const float* Wo = (const float*)d_in[7];
  const float* bo = (const float*)d_in[8];
  float* out = (float*)d_out;
  float* attn = out + 8388608;  // [64 heads][1024][1024] fp32 output

  char* ws = (char*)d_ws;
  f16* xb  = (f16*)(ws);                     // 16MB  (reused as ctx after qkv)
  f16* ctx = (f16*)(ws);                     // alias of xb
  f16* WTq = (f16*)(ws + (16u << 20));       // 2MB each
  f16* WTk = (f16*)(ws + (18u << 20));
  f16* WTv = (f16*)(ws + (20u << 20));
  f16* WTo = (f16*)(ws + (22u << 20));
  f16* q   = (f16*)(ws + (24u << 20));       // 16MB [64][1024][128]
  f16* kk  = (f16*)(ws + (40u << 20));       // 16MB
  f16* vT  = (f16*)(ws + (56u << 20));       // 16MB [64][128][1024]
  // total ws use: 72MB

  cast_f32_f16<<<dim3(8192), dim3(256), 0, stream>>>(x, xb, 8388608);
  transpose_cast<<<dim3(32, 32, 4), dim3(32, 8), 0, stream>>>(
      Wq, Wk, Wv, Wo, WTq, WTk, WTv, WTo);
  qkv_gemm<<<dim3(8, 64, 3), dim3(256), 0, stream>>>(
      xb, WTq, WTk, WTv, bq, bk, bv, q, kk, vT);
  fused_attn<<<dim3(2048), dim3(512), 0, stream>>>(q, kk, vT, attn, ctx);
  out_gemm<<<dim3(8, 64), dim3(256), 0, stream>>>(ctx, WTo, bo, out);
}

// Round 7
// 582.846 us; speedup vs baseline: 1.2914x; 1.0389x over previous
//
#include <hip/hip_runtime.h>

#define DEV __device__ __forceinline__

typedef _Float16 f16;
typedef _Float16 f16x8 __attribute__((ext_vector_type(8)));
typedef _Float16 f16x4 __attribute__((ext_vector_type(4)));
typedef _Float16 h2 __attribute__((ext_vector_type(2)));
typedef float f32x4 __attribute__((ext_vector_type(4)));

#if __has_builtin(__builtin_amdgcn_fdot2)
#define FDOT2(a, b, c) __builtin_amdgcn_fdot2((a), (b), (c), false)
#else
DEV float FDOT2(h2 a, h2 b, float c) {
  return c + (float)a[0] * (float)b[0] + (float)a[1] * (float)b[1];
}
#endif

// ---------------------------------------------------------------- helpers

DEV void gload_lds16(const f16* g, f16* l) {
  // 16B-per-lane async global->LDS. LDS dest is wave-uniform base + lane*16.
  __builtin_amdgcn_global_load_lds(
      (const __attribute__((address_space(1))) void*)g,
      (__attribute__((address_space(3))) void*)l, 16, 0, 0);
}

// ---------------------------------------------------------------- prep

__global__ __launch_bounds__(256) void cast_f32_f16(const float* __restrict__ in,
                                                    f16* __restrict__ out, int n) {
  int i = (blockIdx.x * 256 + threadIdx.x) * 8;
  if (i < n) {
    float4 f0 = *(const float4*)(in + i);
    float4 f1 = *(const float4*)(in + i + 4);
    f16x8 o = {(f16)f0.x, (f16)f0.y, (f16)f0.z, (f16)f0.w,
               (f16)f1.x, (f16)f1.y, (f16)f1.z, (f16)f1.w};
    *(f16x8*)(out + i) = o;  // 16B coalesced store
  }
}

// transpose + cast 1024x1024 fp32 W -> f16 W^T, 64x64 tiles, packed 8B stores
__global__ __launch_bounds__(256) void transpose_cast(
    const float* s0, const float* s1, const float* s2, const float* s3,
    f16* d0, f16* d1, f16* d2, f16* d3) {
  const float* S[4] = {s0, s1, s2, s3};
  f16* D[4] = {d0, d1, d2, d3};
  const float* W = S[blockIdx.z];
  f16* WT = D[blockIdx.z];
  __shared__ float tile[64 * 66];
  const int t = threadIdx.x;
  const int r0 = blockIdx.y * 64, c0 = blockIdx.x * 64;
  const int lr = t >> 6, lc = t & 63;
#pragma unroll
  for (int i = 0; i < 16; i++)
    tile[(i * 4 + lr) * 66 + lc] = W[(r0 + i * 4 + lr) * 1024 + c0 + lc];
  __syncthreads();
  const int wc = t >> 4;          // 0..15
  const int wr4 = (t & 15) * 4;   // 0..60
#pragma unroll
  for (int j = 0; j < 4; j++) {
    int cc = j * 16 + wc;
    f16x4 pk = {(f16)tile[(wr4 + 0) * 66 + cc], (f16)tile[(wr4 + 1) * 66 + cc],
                (f16)tile[(wr4 + 2) * 66 + cc], (f16)tile[(wr4 + 3) * 66 + cc]};
    *(f16x4*)(WT + (size_t)(c0 + cc) * 1024 + r0 + wr4) = pk;  // 8B, 128B/16 lanes
  }
}

// ---------------------------------------------------------------- BT-GEMM core (m97)

DEV void gemm_bt_f16(const f16* __restrict__ A, const f16* __restrict__ B,
                     int lda, int ldb, int K, f16* As, f16* Bs, f32x4 (&acc)[4][4]) {
  const int t = threadIdx.x;
  const int l = t & 63, w = t >> 6;
  const int wm = w >> 1, wn = w & 1;
  const f16* ag = A + (t >> 2) * lda + (t & 3) * 8;
  const f16* bg = B + (t >> 2) * ldb + (t & 3) * 8;
  f16* asd = As + w * 512;
  f16* bsd = Bs + w * 512;
  const int arow = wm * 64 + (l & 15);
  const int brow = wn * 64 + (l & 15);
  const int ko = (l >> 4) * 8;
  for (int k0 = 0; k0 < K; k0 += 32) {
    __syncthreads();
    gload_lds16(ag + k0, asd);
    gload_lds16(ag + 64 * lda + k0, asd + 2048);
    gload_lds16(bg + k0, bsd);
    gload_lds16(bg + 64 * ldb + k0, bsd + 2048);
    __syncthreads();
    f16x8 af[4], bf[4];
#pragma unroll
    for (int i = 0; i < 4; i++) af[i] = *(const f16x8*)(As + (arow + i * 16) * 32 + ko);
#pragma unroll
    for (int j = 0; j < 4; j++) bf[j] = *(const f16x8*)(Bs + (brow + j * 16) * 32 + ko);
#pragma unroll
    for (int i = 0; i < 4; i++)
#pragma unroll
      for (int j = 0; j < 4; j++)
        acc[i][j] = __builtin_amdgcn_mfma_f32_16x16x32_f16(af[i], bf[j], acc[i][j], 0, 0, 0);
  }
}

// ---------------------------------------------------------------- K1: QKV projection
// Epilogue now routes q/k through LDS (like v) for 16B coalesced stores:
// per block the q/k destination is one contiguous 32KB region.

__global__ __launch_bounds__(256) void qkv_gemm(
    const f16* __restrict__ xb, const f16* __restrict__ WTq, const f16* __restrict__ WTk,
    const f16* __restrict__ WTv, const float* __restrict__ bq, const float* __restrict__ bk,
    const float* __restrict__ bv, f16* __restrict__ q, f16* __restrict__ kk,
    f16* __restrict__ vT) {
  __shared__ f16 As[128 * 32];
  __shared__ f16 Bs[128 * 32];
  __shared__ f16 tr[128 * 136];  // stride 136: 16B-aligned rows, 2-way-free banks
  const int z = blockIdx.z;
  const f16* WT = (z == 0) ? WTq : ((z == 1) ? WTk : WTv);
  const float* bias = (z == 0) ? bq : ((z == 1) ? bk : bv);
  const int rowBase = blockIdx.y * 128, colBase = blockIdx.x * 128;
  f32x4 zero4 = {0.f, 0.f, 0.f, 0.f};
  f32x4 acc[4][4];
#pragma unroll
  for (int i = 0; i < 4; i++)
#pragma unroll
    for (int j = 0; j < 4; j++) acc[i][j] = zero4;
  gemm_bt_f16(xb + rowBase * 1024, WT + colBase * 1024, 1024, 1024, 1024, As, Bs, acc);
  const int t = threadIdx.x, l = t & 63, w = t >> 6, wm = w >> 1, wn = w & 1;
  const int b = blockIdx.y >> 3, h = blockIdx.x;
  const int nb = (blockIdx.y & 7) * 128;
  const int head = b * 8 + h;
  float b4[4];
#pragma unroll
  for (int j = 0; j < 4; j++) b4[j] = bias[colBase + wn * 64 + j * 16 + (l & 15)];
  if (z < 2) {
    f16* dst = (z == 0) ? q : kk;
#pragma unroll
    for (int i = 0; i < 4; i++)
#pragma unroll
      for (int j = 0; j < 4; j++)
#pragma unroll
        for (int r = 0; r < 4; r++) {
          int rt = wm * 64 + i * 16 + ((l >> 4) << 2) + r;
          int ct = wn * 64 + j * 16 + (l & 15);
          tr[rt * 136 + ct] = (f16)(acc[i][j][r] + b4[j]);
        }
    __syncthreads();
    f16* dstb = dst + ((size_t)head * 1024 + nb) * 128;  // contiguous 32KB
#pragma unroll
    for (int p = 0; p < 8; p++) {
      int lin = p * 2048 + t * 8;
      int rt = lin >> 7, ct = lin & 127;
      f16x8 v = *(const f16x8*)(&tr[rt * 136 + ct]);
      *(f16x8*)(dstb + lin) = v;
    }
  } else {
#pragma unroll
    for (int i = 0; i < 4; i++)
#pragma unroll
      for (int j = 0; j < 4; j++)
#pragma unroll
        for (int r = 0; r < 4; r++) {
          int rt = wm * 64 + i * 16 + ((l >> 4) << 2) + r;
          int ct = wn * 64 + j * 16 + (l & 15);
          tr[ct * 136 + rt] = (f16)(acc[i][j][r] + b4[j]);
        }
    __syncthreads();
#pragma unroll
    for (int p = 0; p < 8; p++) {
      int lin = p * 2048 + t * 8;
      int c = lin >> 7, r = lin & 127;
      f16x8 v = *(const f16x8*)(&tr[c * 136 + r]);
      *(f16x8*)(vT + head * 131072 + c * 1024 + nb + r) = v;
    }
  }
}

// ---------------------------------------------------------------- K2: fused scores+entmax+PV, v5
// R6 structure (M=32 strip, barrier-free dataflow, XCD-aware head placement,
// FETCH 24.6MB verified) with the entmax core rebuilt in packed f16:
// v_pk_sub/v_pk_max + v_dot2_f32_f16 -> 2 elements per 3 VALU instrs (was 1
// per 3 in f32). f16 eval error in Sigma ~1e-3 -> tau shift ~2.5e-4, attn
// error ~5e-4 << 1.2e-2 threshold. 12 bisection iters (trunc 2.4e-4).

#define PSLD 1032  // +8 pad

__global__ __launch_bounds__(512, 4) void fused_attn(
    const f16* __restrict__ q, const f16* __restrict__ kk,
    const f16* __restrict__ vT, float* __restrict__ attn, f16* __restrict__ ctx) {
  __shared__ f16 Ps[32 * PSLD];  // 66 KB
  const int t = threadIdx.x, l = t & 63, w = t >> 6;
  const int blk = blockIdx.x;          // 0..2047
  const int xcd = blk & 7;
  const int slot = blk >> 3;           // 0..255
  const int head = xcd * 8 + (slot >> 5);
  const int n0 = (slot & 31) * 32;
  const int l15 = l & 15, l16 = l >> 4;
  const int bb = head >> 3, hh = head & 7;
  const float SC = 0.04419417382415922f;  // (alpha-1)/sqrt(D) = 0.5/sqrt(128)

  const f16* qh = q + head * 131072;
  const f16* kh = kk + head * 131072;
  const f16* vh = vT + head * 131072;

  // q A-fragments for both m-tiles (rows n0..n0+31), kept in registers
  f16x8 qf[2][4];
#pragma unroll
  for (int mt = 0; mt < 2; mt++)
#pragma unroll
    for (int kb = 0; kb < 4; kb++)
      qf[mt][kb] = *(const f16x8*)(qh + (n0 + mt * 16 + l15) * 128 + kb * 32 + l16 * 8);

  // ---- phase 1: scores (wave w owns n-tiles w*8 .. w*8+7) ---------------
#pragma unroll 4
  for (int i = 0; i < 8; i++) {
    const int nt = w * 8 + i;
    f16x8 bf[4];
#pragma unroll
    for (int kb = 0; kb < 4; kb++)
      bf[kb] = *(const f16x8*)(kh + (nt * 16 + l15) * 128 + kb * 32 + l16 * 8);
    f32x4 acc[2] = {{0.f, 0.f, 0.f, 0.f}, {0.f, 0.f, 0.f, 0.f}};
#pragma unroll
    for (int mt = 0; mt < 2; mt++)
#pragma unroll
      for (int kb = 0; kb < 4; kb++)
        acc[mt] = __builtin_amdgcn_mfma_f32_16x16x32_f16(qf[mt][kb], bf[kb], acc[mt], 0, 0, 0);
#pragma unroll
    for (int mt = 0; mt < 2; mt++)
#pragma unroll
      for (int r = 0; r < 4; r++)
        Ps[(mt * 16 + l16 * 4 + r) * PSLD + nt * 16 + l15] = (f16)(acc[mt][r] * SC);
  }
  __syncthreads();

  // ---- phase 2: entmax, packed-f16 core (wave w: rows w*4..w*4+3) -------
  const h2 z2 = {(f16)0.f, (f16)0.f};
  for (int p = 0; p < 2; p++) {
    f16* r0p = Ps + (size_t)(w * 4 + p * 2) * PSLD;
    f16* r1p = r0p + PSLD;
    f16x8 A0 = *(const f16x8*)(r0p + l * 8);
    f16x8 A1 = *(const f16x8*)(r0p + 512 + l * 8);
    f16x8 B0 = *(const f16x8*)(r1p + l * 8);
    f16x8 B1 = *(const f16x8*)(r1p + 512 + l * 8);
    h2 a[8], b[8];
#pragma unroll
    for (int e = 0; e < 4; e++) {
      a[e] = h2{A0[2 * e], A0[2 * e + 1]};
      a[e + 4] = h2{A1[2 * e], A1[2 * e + 1]};
      b[e] = h2{B0[2 * e], B0[2 * e + 1]};
      b[e + 4] = h2{B1[2 * e], B1[2 * e + 1]};
    }
    h2 ma = a[0], mb = b[0];
#pragma unroll
    for (int e = 1; e < 8; e++) {
      ma = __builtin_elementwise_max(ma, a[e]);
      mb = __builtin_elementwise_max(mb, b[e]);
    }
    float m0 = fmaxf((float)ma[0], (float)ma[1]);
    float m1 = fmaxf((float)mb[0], (float)mb[1]);
#pragma unroll
    for (int o = 32; o; o >>= 1) {
      m0 = fmaxf(m0, __shfl_xor(m0, o, 64));
      m1 = fmaxf(m1, __shfl_xor(m1, o, 64));
    }
    float lo0 = m0 - 1.0f, lo1 = m1 - 1.0f;
    float dm = 0.96875f;  // 1 - (1/1024)^(alpha-1)
    float tm0 = lo0, tm1 = lo1;
    for (int it = 0; it < 12; ++it) {
      dm *= 0.5f;
      tm0 = lo0 + dm; tm1 = lo1 + dm;
      f16 th0 = (f16)tm0, th1 = (f16)tm1;
      h2 t0 = {th0, th0}, t1 = {th1, th1};
      float s0 = 0.f, s1 = 0.f;
#pragma unroll
      for (int e = 0; e < 8; e++) {
        h2 d0 = __builtin_elementwise_max(a[e] - t0, z2);
        h2 d1 = __builtin_elementwise_max(b[e] - t1, z2);
        s0 = FDOT2(d0, d0, s0);
        s1 = FDOT2(d1, d1, s1);
      }
#pragma unroll
      for (int o = 32; o; o >>= 1) { s0 += __shfl_xor(s0, o, 64); s1 += __shfl_xor(s1, o, 64); }
      if (s0 >= 1.0f) lo0 = tm0;  // f_lo >= 0 always (tau_lo = max-1) => test sm>=1
      if (s1 >= 1.0f) lo1 = tm1;
    }
    // final pass at tau_m in f32
    f16 th0 = (f16)tm0, th1 = (f16)tm1;
    h2 t0 = {th0, th0}, t1 = {th1, th1};
    float pa[16], pb[16];
    float q0 = 0.f, q1 = 0.f;
#pragma unroll
    for (int e = 0; e < 8; e++) {
      h2 d0 = __builtin_elementwise_max(a[e] - t0, z2);
      h2 d1 = __builtin_elementwise_max(b[e] - t1, z2);
      float f0 = (float)d0[0], f1 = (float)d0[1];
      float g0 = (float)d1[0], g1 = (float)d1[1];
      pa[2 * e] = f0 * f0; pa[2 * e + 1] = f1 * f1;
      pb[2 * e] = g0 * g0; pb[2 * e + 1] = g1 * g1;
      q0 += pa[2 * e] + pa[2 * e + 1];
      q1 += pb[2 * e] + pb[2 * e + 1];
    }
#pragma unroll
    for (int o = 32; o; o >>= 1) { q0 += __shfl_xor(q0, o, 64); q1 += __shfl_xor(q1, o, 64); }
    float i0 = 1.0f / q0, i1 = 1.0f / q1;
    float* a0p = attn + ((size_t)head * 1024 + n0 + w * 4 + p * 2) * 1024;
    float* a1p = a0p + 1024;
    float4 v0 = {pa[0] * i0, pa[1] * i0, pa[2] * i0, pa[3] * i0};
    float4 v1 = {pa[4] * i0, pa[5] * i0, pa[6] * i0, pa[7] * i0};
    float4 v2 = {pa[8] * i0, pa[9] * i0, pa[10] * i0, pa[11] * i0};
    float4 v3 = {pa[12] * i0, pa[13] * i0, pa[14] * i0, pa[15] * i0};
    float4 u0 = {pb[0] * i1, pb[1] * i1, pb[2] * i1, pb[3] * i1};
    float4 u1 = {pb[4] * i1, pb[5] * i1, pb[6] * i1, pb[7] * i1};
    float4 u2 = {pb[8] * i1, pb[9] * i1, pb[10] * i1, pb[11] * i1};
    float4 u3 = {pb[12] * i1, pb[13] * i1, pb[14] * i1, pb[15] * i1};
    *(float4*)(a0p + l * 8) = v0;
    *(float4*)(a0p + l * 8 + 4) = v1;
    *(float4*)(a0p + 512 + l * 8) = v2;
    *(float4*)(a0p + 512 + l * 8 + 4) = v3;
    *(float4*)(a1p + l * 8) = u0;
    *(float4*)(a1p + l * 8 + 4) = u1;
    *(float4*)(a1p + 512 + l * 8) = u2;
    *(float4*)(a1p + 512 + l * 8 + 4) = u3;
    f16x8 o0 = {(f16)v0.x, (f16)v0.y, (f16)v0.z, (f16)v0.w,
                (f16)v1.x, (f16)v1.y, (f16)v1.z, (f16)v1.w};
    f16x8 o1 = {(f16)v2.x, (f16)v2.y, (f16)v2.z, (f16)v2.w,
                (f16)v3.x, (f16)v3.y, (f16)v3.z, (f16)v3.w};
    f16x8 o2 = {(f16)u0.x, (f16)u0.y, (f16)u0.z, (f16)u0.w,
                (f16)u1.x, (f16)u1.y, (f16)u1.z, (f16)u1.w};
    f16x8 o3 = {(f16)u2.x, (f16)u2.y, (f16)u2.z, (f16)u2.w,
                (f16)u3.x, (f16)u3.y, (f16)u3.z, (f16)u3.w};
    *(f16x8*)(r0p + l * 8) = o0;
    *(f16x8*)(r0p + 512 + l * 8) = o1;
    *(f16x8*)(r1p + l * 8) = o2;
    *(f16x8*)(r1p + 512 + l * 8) = o3;
  }
  __syncthreads();

  // ---- phase 3: ctx = P @ V (wave w owns d-tile w; K=1024 dataflow) -----
  f32x4 cacc[2] = {{0.f, 0.f, 0.f, 0.f}, {0.f, 0.f, 0.f, 0.f}};
#pragma unroll 8
  for (int kb = 0; kb < 32; kb++) {
    f16x8 bfv = *(const f16x8*)(vh + (w * 16 + l15) * 1024 + kb * 32 + l16 * 8);
    f16x8 af0 = *(const f16x8*)(Ps + l15 * PSLD + kb * 32 + l16 * 8);
    f16x8 af1 = *(const f16x8*)(Ps + (16 + l15) * PSLD + kb * 32 + l16 * 8);
    cacc[0] = __builtin_amdgcn_mfma_f32_16x16x32_f16(af0, bfv, cacc[0], 0, 0, 0);
    cacc[1] = __builtin_amdgcn_mfma_f32_16x16x32_f16(af1, bfv, cacc[1], 0, 0, 0);
  }
#pragma unroll
  for (int mt = 0; mt < 2; mt++)
#pragma unroll
    for (int r = 0; r < 4; r++) {
      int m = mt * 16 + l16 * 4 + r;
      int d = w * 16 + l15;
      ctx[(size_t)(bb * 1024 + n0 + m) * 1024 + hh * 128 + d] = (f16)cacc[mt][r];
    }
}

// ---------------------------------------------------------------- K3: out = ctx @ Wo + bo

__global__ __launch_bounds__(256) void out_gemm(const f16* __restrict__ ctx,
                                                const f16* __restrict__ WTo,
                                                const float* __restrict__ bo,
                                                float* __restrict__ out) {
  __shared__ f16 As[128 * 32];
  __shared__ f16 Bs[128 * 32];
  const int rowBase = blockIdx.y * 128, colBase = blockIdx.x * 128;
  f32x4 zero4 = {0.f, 0.f, 0.f, 0.f};
  f32x4 acc[4][4];
#pragma unroll
  for (int i = 0; i < 4; i++)
#pragma unroll
    for (int j = 0; j < 4; j++) acc[i][j] = zero4;
  gemm_bt_f16(ctx + rowBase * 1024, WTo + colBase * 1024, 1024, 1024, 1024, As, Bs, acc);
  const int l = threadIdx.x & 63, w = threadIdx.x >> 6, wm = w >> 1, wn = w & 1;
#pragma unroll
  for (int i = 0; i < 4; i++)
#pragma unroll
    for (int j = 0; j < 4; j++)
#pragma unroll
      for (int r = 0; r < 4; r++) {
        int rt = wm * 64 + i * 16 + ((l >> 4) << 2) + r;
        int ct = wn * 64 + j * 16 + (l & 15);
        out[(size_t)(rowBase + rt) * 1024 + colBase + ct] = acc[i][j][r] + bo[colBase + ct];
      }
}

// ---------------------------------------------------------------- launch

extern "C" void kernel_launch(void* const* d_in, const int* in_sizes, int n_in,
                              void* d_out, int out_size, void* d_ws, size_t ws_size,
                              hipStream_t stream) {
  const float* x  = (const float*)d_in[0];
  const float* Wq = (const float*)d_in[1];
  const float* bq = (const float*)d_in[2];
  const float* Wk = (const float*)d_in[3];
  const float* bk = (const float*)d_in[4];
  const float* Wv = (const float*)d_in[5];
  const float* bv = (const float*)d_in[6];
  const float* Wo = (const float*)d_in[7];
  const float* bo = (const float*)d_in[8];
  float* out = (float*)d_out;
  float* attn = out + 8388608;  // [64 heads][1024][1024] fp32 output

  char* ws = (char*)d_ws;
  f16* xb  = (f16*)(ws);                     // 16MB  (reused as ctx after qkv)
  f16* ctx = (f16*)(ws);                     // alias of xb
  f16* WTq = (f16*)(ws + (16u << 20));       // 2MB each
  f16* WTk = (f16*)(ws + (18u << 20));
  f16* WTv = (f16*)(ws + (20u << 20));
  f16* WTo = (f16*)(ws + (22u << 20));
  f16* q   = (f16*)(ws + (24u << 20));       // 16MB [64][1024][128]
  f16* kk  = (f16*)(ws + (40u << 20));       // 16MB
  f16* vT  = (f16*)(ws + (56u << 20));       // 16MB [64][128][1024]
  // total ws use: 72MB

  cast_f32_f16<<<dim3(4096), dim3(256), 0, stream>>>(x, xb, 8388608);
  transpose_cast<<<dim3(16, 16, 4), dim3(256), 0, stream>>>(
      Wq, Wk, Wv, Wo, WTq, WTk, WTv, WTo);
  qkv_gemm<<<dim3(8, 64, 3), dim3(256), 0, stream>>>(
      xb, WTq, WTk, WTv, bq, bk, bv, q, kk, vT);
  fused_attn<<<dim3(2048), dim3(512), 0, stream>>>(q, kk, vT, attn, ctx);
  out_gemm<<<dim3(8, 64), dim3(256), 0, stream>>>(ctx, WTo, bo, out);
}